// Round 7
// baseline (6304.093 us; speedup 1.0000x reference)
//
#include <hip/hip_runtime.h>
#include <cmath>

// MultiLayerRNN: B=64, T=1024, D=256, H=512, O=256, L=2 (all fp32)
//
// R14: two-rows-per-block phase-offset scan (latency hiding).
// R13 failed because 768-block coop launch exceeded co-residency (216
// regs/wave -> 1 block/CU) and silently no-opped. Fusion across layers is
// register-infeasible. Instead: hide the exchange latency WITHIN a scan.
// 128 blocks: block (q,p) runs rows {2p,2p+1} with the SAME pinned Whh
// quarter-slice (no extra registers). Iteration interleaves the rows:
//   detectA, MACA, barrier, [epi: reduceA+publishA] / others start
//   detectB, MACB, barrier, [epi: reduceB+publishB]
// A's publish->detect gap is filled by the whole B phase (~900+ cyc) and
// vice versa -> polls become first-probe hits instead of dead waiting.
// Per-row protocol is BYTE-IDENTICAL to R12 (tags, parity-2 ring, sc0
// publish + MALL fallback, fast/fast/MALL poll, MAC order, 12-bit h
// quantization) -> same overwrite-safety proof, same numerics.
// bi = q*32+p: all 4 quarter-blocks of a pair ≡ p (mod 8) -> same XCD
// under round-robin (proven R9). gemm/fc: exact R0 known-good code.

#define Bdim 64
#define Tdim 1024
#define Ddim 256
#define Hdim 512
#define Odim 256

// ---------------- row-blocked GEMM (EXACT R0 code, known-good) ----------------
template <int K>
__global__ __launch_bounds__(1024) void gemm_rows(const float* A, const float* W,
                                                  const float* __restrict__ bias_a,
                                                  const float* __restrict__ bias_b,
                                                  float* C) {
  constexpr int KT = 16;
  __shared__ __align__(16) float As[64][KT];
  __shared__ __align__(16) float Ws[KT][516];
  const int t = threadIdx.x;
  const size_t row0 = (size_t)blockIdx.x * 64;
  const int tn = t & 127;
  const int tm = t >> 7;

  float acc[8][4];
#pragma unroll
  for (int i = 0; i < 8; ++i)
#pragma unroll
    for (int j = 0; j < 4; ++j) acc[i][j] = 0.f;

  const int r_st = t >> 4;
  const int k_st = t & 15;

  for (int k0 = 0; k0 < K; k0 += KT) {
    As[r_st][k_st] = A[(row0 + r_st) * K + k0 + k_st];
#pragma unroll
    for (int rep = 0; rep < 8; ++rep) {
      const int idx = rep * 1024 + t;
      const int n = idx >> 4;
      const int kk = idx & 15;
      Ws[kk][n] = W[(size_t)n * K + k0 + kk];
    }
    __syncthreads();
#pragma unroll
    for (int kk = 0; kk < KT; ++kk) {
      float a[8];
#pragma unroll
      for (int i = 0; i < 8; ++i) a[i] = As[tm * 8 + i][kk];
      const float4 w = *(const float4*)&Ws[kk][tn * 4];
#pragma unroll
      for (int i = 0; i < 8; ++i) {
        acc[i][0] = fmaf(a[i], w.x, acc[i][0]);
        acc[i][1] = fmaf(a[i], w.y, acc[i][1]);
        acc[i][2] = fmaf(a[i], w.z, acc[i][2]);
        acc[i][3] = fmaf(a[i], w.w, acc[i][3]);
      }
    }
    __syncthreads();
  }
  float bn[4];
#pragma unroll
  for (int j = 0; j < 4; ++j) bn[j] = bias_a[tn * 4 + j] + bias_b[tn * 4 + j];
#pragma unroll
  for (int i = 0; i < 8; ++i) {
    float4 v;
    v.x = acc[i][0] + bn[0];
    v.y = acc[i][1] + bn[1];
    v.z = acc[i][2] + bn[2];
    v.w = acc[i][3] + bn[3];
    *(float4*)&C[(row0 + tm * 8 + i) * (size_t)Hdim + tn * 4] = v;
  }
}

__device__ __forceinline__ float fast_tanh(float y) {
  // exact identity: tanh(y) = 1 - 2/(exp(2y)+1). |err| ~1e-7.
  const float e2 = __expf(2.0f * y);
  return 1.0f - 2.0f * __builtin_amdgcn_rcpf(e2 + 1.0f);
}

// fast-path primitives: local-XCD L2
__device__ __forceinline__ unsigned ld_l2_sc0(const unsigned* p) {
  unsigned v;
  asm volatile("global_load_dword %0, %1, off sc0\n\ts_waitcnt vmcnt(0)"
               : "=v"(v)
               : "v"(p)
               : "memory");
  return v;
}
__device__ __forceinline__ void st_l2_sc0(unsigned* p, unsigned v) {
  asm volatile("global_store_dword %0, %1, off sc0" ::"v"(p), "v"(v) : "memory");
}

// ---------------- two-row phase-offset scan ----------------
// Block bi = q*32 + p: quarter q, row pair {2p, 2p+1}. Wave w consumes
// k-slice [64w,64w+64); lane l holds W rows {q*128+2l, q*128+2l+1} pinned.
// Epilogue waves: w in {2q,2q+1} (their k-slices equal their published range).
__global__ __launch_bounds__(512, 2) void rnn_scan2(
    float* xw,                       // [B][T][512]
    const float* __restrict__ Whh,   // [512][512] row-major (j,k)
    unsigned* hbuf,                  // [2][B][512] tagged dwords, MALL path
    unsigned* fbuf,                  // [2][B][512] tagged dwords, L2 path
    float* h_final,                  // [B][512] or null
    const int store_seq) {
  const int bi = blockIdx.x;
  const int p = bi & 31;  // row pair
  const int q = bi >> 5;  // output quarter
  const int rA = 2 * p;
  const int rB = 2 * p + 1;
  const int t = threadIdx.x;
  const int w = t >> 6;  // wave id, uniform
  const int l = t & 63;
  const int jg0 = q * 128 + 2 * l;      // global W rows {jg0, jg0+1}
  const bool is_epi = ((w >> 1) == q);  // wave-uniform role

  __shared__ __align__(16) float hLA[2][Hdim];
  __shared__ __align__(16) float hLB[2][Hdim];
  __shared__ __align__(16) float redA[2][8][128];
  __shared__ __align__(16) float redB[2][8][128];

  // ---- load W slice (2 rows x 64 k) and pin in registers ----
  float4 W0[16], W1[16];
  {
    const float4* w0p = (const float4*)(Whh + (size_t)jg0 * Hdim + w * 64);
    const float4* w1p = (const float4*)(Whh + (size_t)(jg0 + 1) * Hdim + w * 64);
#pragma unroll
    for (int c = 0; c < 16; ++c) {
      W0[c] = w0p[c];
      W1[c] = w1p[c];
    }
  }
#pragma unroll
  for (int c = 0; c < 16; ++c) {
    asm volatile("" : "+v"(W0[c].x), "+v"(W0[c].y), "+v"(W0[c].z), "+v"(W0[c].w));
    asm volatile("" : "+v"(W1[c].x), "+v"(W1[c].y), "+v"(W1[c].z), "+v"(W1[c].w));
  }

  hLA[0][t] = 0.0f;  // h_{-1} = 0
  hLB[0][t] = 0.0f;
  __syncthreads();

  float* rowA = xw + (size_t)rA * Tdim * Hdim;
  float* rowB = xw + (size_t)rB * Tdim * Hdim;
  unsigned* hbA = hbuf + rA * Hdim;  // parity-0 bases
  unsigned* fbA = fbuf + rA * Hdim;
  unsigned* hbB = hbuf + rB * Hdim;
  unsigned* fbB = fbuf + rB * Hdim;
  float xvA = is_epi ? rowA[t] : 0.f;  // xw for step 0
  float xvB = is_epi ? rowB[t] : 0.f;

  for (int s = 0; s < Tdim; ++s, rowA += Hdim, rowB += Hdim) {
    const int sp = s & 1;
    const unsigned want = 1024u | ((unsigned)s & 1023u);

    // ================= row A phase =================
    if (s > 0 && !is_epi) {
      const size_t off = (size_t)((s - 1) & 1) * (Bdim * Hdim) + t;
      const unsigned* fp = fbA + off;
      const unsigned* mp = hbA + off;
      unsigned v = ld_l2_sc0(fp);
      if ((v & 2047u) != want) {
        for (;;) {
          v = ld_l2_sc0(fp);
          if ((v & 2047u) == want) break;
          v = ld_l2_sc0(fp);
          if ((v & 2047u) == want) break;
          v = __hip_atomic_load(mp, __ATOMIC_RELAXED, __HIP_MEMORY_SCOPE_AGENT);
          if ((v & 2047u) == want) break;
        }
      }
      hLA[sp][t] = __uint_as_float(v & 0xFFFFF800u);
    }
    {
      const float4* h4 = (const float4*)&hLA[sp][w * 64];
      float a0 = 0.f, a0b = 0.f, a1 = 0.f, a1b = 0.f;
#pragma unroll
      for (int c = 0; c < 16; ++c) {
        const float4 hv = h4[c];
        a0  = fmaf(W0[c].x, hv.x, a0);
        a0b = fmaf(W0[c].y, hv.y, a0b);
        a0  = fmaf(W0[c].z, hv.z, a0);
        a0b = fmaf(W0[c].w, hv.w, a0b);
        a1  = fmaf(W1[c].x, hv.x, a1);
        a1b = fmaf(W1[c].y, hv.y, a1b);
        a1  = fmaf(W1[c].z, hv.z, a1);
        a1b = fmaf(W1[c].w, hv.w, a1b);
      }
      *(float2*)&redA[sp][w][2 * l] = make_float2(a0 + a0b, a1 + a1b);
    }
    __syncthreads();  // barrier 1

    if (is_epi) {
      const int e = t & 127;
      float y = xvA;
#pragma unroll
      for (int w8 = 0; w8 < 8; ++w8) y += redA[sp][w8][e];
      const float hn = fast_tanh(y);
      const unsigned bits = (__float_as_uint(hn) + 0x400u) & 0xFFFFF800u;
      const float hq = __uint_as_float(bits);
      const unsigned pv = bits | 1024u | ((unsigned)(s + 1) & 1023u);
      const size_t off = (size_t)sp * (Bdim * Hdim) + t;
      st_l2_sc0(fbA + off, pv);  // publish ASAP: consumers detect during B phase
      __hip_atomic_store(hbA + off, pv, __ATOMIC_RELAXED,
                         __HIP_MEMORY_SCOPE_AGENT);
      hLA[sp ^ 1][t] = hq;
      if (store_seq) rowA[t] = hq;
      if (s + 1 < Tdim)
        xvA = rowA[Hdim + t];
      else if (h_final != nullptr)
        h_final[(size_t)rA * Hdim + t] = hq;
    }

    // ================= row B phase =================
    if (s > 0 && !is_epi) {
      const size_t off = (size_t)((s - 1) & 1) * (Bdim * Hdim) + t;
      const unsigned* fp = fbB + off;
      const unsigned* mp = hbB + off;
      unsigned v = ld_l2_sc0(fp);
      if ((v & 2047u) != want) {
        for (;;) {
          v = ld_l2_sc0(fp);
          if ((v & 2047u) == want) break;
          v = ld_l2_sc0(fp);
          if ((v & 2047u) == want) break;
          v = __hip_atomic_load(mp, __ATOMIC_RELAXED, __HIP_MEMORY_SCOPE_AGENT);
          if ((v & 2047u) == want) break;
        }
      }
      hLB[sp][t] = __uint_as_float(v & 0xFFFFF800u);
    }
    {
      const float4* h4 = (const float4*)&hLB[sp][w * 64];
      float a0 = 0.f, a0b = 0.f, a1 = 0.f, a1b = 0.f;
#pragma unroll
      for (int c = 0; c < 16; ++c) {
        const float4 hv = h4[c];
        a0  = fmaf(W0[c].x, hv.x, a0);
        a0b = fmaf(W0[c].y, hv.y, a0b);
        a0  = fmaf(W0[c].z, hv.z, a0);
        a0b = fmaf(W0[c].w, hv.w, a0b);
        a1  = fmaf(W1[c].x, hv.x, a1);
        a1b = fmaf(W1[c].y, hv.y, a1b);
        a1  = fmaf(W1[c].z, hv.z, a1);
        a1b = fmaf(W1[c].w, hv.w, a1b);
      }
      *(float2*)&redB[sp][w][2 * l] = make_float2(a0 + a0b, a1 + a1b);
    }
    __syncthreads();  // barrier 2

    if (is_epi) {
      const int e = t & 127;
      float y = xvB;
#pragma unroll
      for (int w8 = 0; w8 < 8; ++w8) y += redB[sp][w8][e];
      const float hn = fast_tanh(y);
      const unsigned bits = (__float_as_uint(hn) + 0x400u) & 0xFFFFF800u;
      const float hq = __uint_as_float(bits);
      const unsigned pv = bits | 1024u | ((unsigned)(s + 1) & 1023u);
      const size_t off = (size_t)sp * (Bdim * Hdim) + t;
      st_l2_sc0(fbB + off, pv);
      __hip_atomic_store(hbB + off, pv, __ATOMIC_RELAXED,
                         __HIP_MEMORY_SCOPE_AGENT);
      hLB[sp ^ 1][t] = hq;
      if (store_seq) rowB[t] = hq;
      if (s + 1 < Tdim)
        xvB = rowB[Hdim + t];
      else if (h_final != nullptr)
        h_final[(size_t)rB * Hdim + t] = hq;
    }
  }
}

// ---------------- final FC ----------------
__global__ __launch_bounds__(256) void fc_kernel(const float* __restrict__ h,
                                                 const float* __restrict__ Wfc,
                                                 const float* __restrict__ bfc,
                                                 float* __restrict__ out) {
  __shared__ float hs[Hdim];
  const int b = blockIdx.x, o = threadIdx.x;
  hs[o] = h[(size_t)b * Hdim + o];
  hs[o + 256] = h[(size_t)b * Hdim + 256 + o];
  __syncthreads();
  float acc = bfc[o];
  const float* wr = Wfc + (size_t)o * Hdim;
#pragma unroll 4
  for (int k = 0; k < Hdim; k += 4) {
    const float4 w = *(const float4*)(wr + k);
    acc = fmaf(w.x, hs[k], acc);
    acc = fmaf(w.y, hs[k + 1], acc);
    acc = fmaf(w.z, hs[k + 2], acc);
    acc = fmaf(w.w, hs[k + 3], acc);
  }
  out[(size_t)b * Odim + o] = acc;
}

extern "C" void kernel_launch(void* const* d_in, const int* in_sizes, int n_in,
                              void* d_out, int out_size, void* d_ws, size_t ws_size,
                              hipStream_t stream) {
  const float* x = (const float*)d_in[0];
  const float* W_ih0 = (const float*)d_in[1];
  const float* W_hh0 = (const float*)d_in[2];
  const float* b_ih0 = (const float*)d_in[3];
  const float* b_hh0 = (const float*)d_in[4];
  const float* W_ih1 = (const float*)d_in[5];
  const float* W_hh1 = (const float*)d_in[6];
  const float* b_ih1 = (const float*)d_in[7];
  const float* b_hh1 = (const float*)d_in[8];
  const float* W_fc = (const float*)d_in[9];
  const float* b_fc = (const float*)d_in[10];
  float* out = (float*)d_out;

  float* A = (float*)d_ws;                               // 134 MB
  unsigned* hbuf0 = (unsigned*)(A + (size_t)Bdim * Tdim * Hdim);  // 256 KB
  unsigned* hbuf1 = hbuf0 + (size_t)2 * Bdim * Hdim;              // 256 KB
  unsigned* fbuf0 = hbuf1 + (size_t)2 * Bdim * Hdim;              // 256 KB
  unsigned* fbuf1 = fbuf0 + (size_t)2 * Bdim * Hdim;              // 256 KB
  float* hT1 = (float*)(fbuf1 + (size_t)2 * Bdim * Hdim);         // 128 KB
  // ws poison (0xAA..): low-11 tag = 682, tags live in [1024,2047] -> no match.
  // Per-layer buffers avoid cross-dispatch tag collisions.

  // A = x @ W_ih0^T + b_ih0 + b_hh0
  gemm_rows<Ddim><<<(Bdim * Tdim) / 64, 1024, 0, stream>>>(x, W_ih0, b_ih0, b_hh0, A);

  // layer-0 scan: A <- out0 (in place), 128 two-row blocks
  {
    float* xwp = A;
    const float* W = W_hh0;
    unsigned* hb = hbuf0;
    unsigned* fb = fbuf0;
    float* hf = nullptr;
    int ss = 1;
    void* args[] = {&xwp, (void*)&W, &hb, &fb, &hf, &ss};
    hipLaunchCooperativeKernel((void*)rnn_scan2, dim3(Bdim * 2), dim3(512),
                               args, 0, stream);
  }

  // A <- A @ W_ih1^T + b_ih1 + b_hh1 (in place)
  gemm_rows<Hdim><<<(Bdim * Tdim) / 64, 1024, 0, stream>>>(A, W_ih1, b_ih1, b_hh1, A);

  // layer-1 scan: final hidden only
  {
    float* xwp = A;
    const float* W = W_hh1;
    unsigned* hb = hbuf1;
    unsigned* fb = fbuf1;
    float* hf = hT1;
    int ss = 0;
    void* args[] = {&xwp, (void*)&W, &hb, &fb, &hf, &ss};
    hipLaunchCooperativeKernel((void*)rnn_scan2, dim3(Bdim * 2), dim3(512),
                               args, 0, stream);
  }

  // out = hT1 @ W_fc^T + b_fc
  fc_kernel<<<Bdim, Odim, 0, stream>>>(hT1, W_fc, b_fc, out);
}

// Round 8
// 3587.809 us; speedup vs baseline: 1.7571x; 1.7571x over previous
//
#include <hip/hip_runtime.h>
#include <cmath>

// MultiLayerRNN: B=64, T=1024, D=256, H=512, O=256, L=2 (all fp32)
//
// R15: R12 (best measured config) + ONE change: dual-path poll.
// R14's 2-row experiment measured the exchange constant: each phase cost a
// full R12 step -> publish->remote-detect latency V ~ 2500-3000 cyc gates
// every step; compute chain is only ~550 cyc. V = store-visibility +
// detection quantization. R12's {fast,fast,MALL} rotation samples the
// authoritative MALL path once per ~1500 cyc -> up to ~1500 cyc of
// detection quantization. Fix: issue the L2 probe AND the MALL probe
// together under one vmcnt(0) -> round period = one MALL round trip
// (~700-900 cyc), authoritative path sampled EVERY round. Publish side,
// tags, parity-2 ring, MAC order, 12-bit h quantization: byte-identical
// to R12 -> same safety proof, same numerics.
// gemm/fc: exact R0 known-good code.

#define Bdim 64
#define Tdim 1024
#define Ddim 256
#define Hdim 512
#define Odim 256

// ---------------- row-blocked GEMM (EXACT R0 code, known-good) ----------------
template <int K>
__global__ __launch_bounds__(1024) void gemm_rows(const float* A, const float* W,
                                                  const float* __restrict__ bias_a,
                                                  const float* __restrict__ bias_b,
                                                  float* C) {
  constexpr int KT = 16;
  __shared__ __align__(16) float As[64][KT];
  __shared__ __align__(16) float Ws[KT][516];
  const int t = threadIdx.x;
  const size_t row0 = (size_t)blockIdx.x * 64;
  const int tn = t & 127;
  const int tm = t >> 7;

  float acc[8][4];
#pragma unroll
  for (int i = 0; i < 8; ++i)
#pragma unroll
    for (int j = 0; j < 4; ++j) acc[i][j] = 0.f;

  const int r_st = t >> 4;
  const int k_st = t & 15;

  for (int k0 = 0; k0 < K; k0 += KT) {
    As[r_st][k_st] = A[(row0 + r_st) * K + k0 + k_st];
#pragma unroll
    for (int rep = 0; rep < 8; ++rep) {
      const int idx = rep * 1024 + t;
      const int n = idx >> 4;
      const int kk = idx & 15;
      Ws[kk][n] = W[(size_t)n * K + k0 + kk];
    }
    __syncthreads();
#pragma unroll
    for (int kk = 0; kk < KT; ++kk) {
      float a[8];
#pragma unroll
      for (int i = 0; i < 8; ++i) a[i] = As[tm * 8 + i][kk];
      const float4 w = *(const float4*)&Ws[kk][tn * 4];
#pragma unroll
      for (int i = 0; i < 8; ++i) {
        acc[i][0] = fmaf(a[i], w.x, acc[i][0]);
        acc[i][1] = fmaf(a[i], w.y, acc[i][1]);
        acc[i][2] = fmaf(a[i], w.z, acc[i][2]);
        acc[i][3] = fmaf(a[i], w.w, acc[i][3]);
      }
    }
    __syncthreads();
  }
  float bn[4];
#pragma unroll
  for (int j = 0; j < 4; ++j) bn[j] = bias_a[tn * 4 + j] + bias_b[tn * 4 + j];
#pragma unroll
  for (int i = 0; i < 8; ++i) {
    float4 v;
    v.x = acc[i][0] + bn[0];
    v.y = acc[i][1] + bn[1];
    v.z = acc[i][2] + bn[2];
    v.w = acc[i][3] + bn[3];
    *(float4*)&C[(row0 + tm * 8 + i) * (size_t)Hdim + tn * 4] = v;
  }
}

__device__ __forceinline__ float fast_tanh(float y) {
  // exact identity: tanh(y) = 1 - 2/(exp(2y)+1). |err| ~1e-7.
  const float e2 = __expf(2.0f * y);
  return 1.0f - 2.0f * __builtin_amdgcn_rcpf(e2 + 1.0f);
}

// R15 dual probe: L2 (sc0) and MALL (sc0 sc1) issued together, one wait.
// Round period = max of the two latencies; authoritative path sampled
// every round (R12 sampled it 1-in-3).
__device__ __forceinline__ void ld_dual(const unsigned* fp, const unsigned* mp,
                                        unsigned& vf, unsigned& vm) {
  asm volatile(
      "global_load_dword %0, %2, off sc0\n\t"
      "global_load_dword %1, %3, off sc0 sc1\n\t"
      "s_waitcnt vmcnt(0)"
      : "=&v"(vf), "=&v"(vm)
      : "v"(fp), "v"(mp)
      : "memory");
}
__device__ __forceinline__ void st_l2_sc0(unsigned* p, unsigned v) {
  asm volatile("global_store_dword %0, %1, off sc0" ::"v"(p), "v"(v) : "memory");
}

// ---------------- role-swapped scan, dual-path L2/MALL exchange ----------------
// R12 structure. Block bi = q*64+b: b (row), q (output quarter); peers of a
// row are same-XCD under round-robin (proven by R9's inversion experiment).
// Wave w consumes k-slice [64w,64w+64); lane l holds W rows {q*128+2l,
// q*128+2l+1}, pinned in regs. Epilogue waves: w in {2q,2q+1}.
__global__ __launch_bounds__(512, 2) void rnn_scan_coop(
    float* xw,                       // [B][T][512]
    const float* __restrict__ Whh,   // [512][512] row-major (j,k)
    unsigned* hbuf,                  // [2][B][512] tagged dwords, MALL path
    unsigned* fbuf,                  // [2][B][512] tagged dwords, L2 path
    float* h_final,                  // [B][512] or null
    const int store_seq) {
  const int bi = blockIdx.x;
  const int b = bi & 63;
  const int q = bi >> 6;
  const int t = threadIdx.x;
  const int w = t >> 6;  // wave id, uniform
  const int l = t & 63;
  const int jg0 = q * 128 + 2 * l;      // global W rows {jg0, jg0+1}
  const bool is_epi = ((w >> 1) == q);  // wave-uniform role

  __shared__ __align__(16) float hL[2][Hdim];
  __shared__ __align__(16) float red[2][8][128];

  // ---- load W slice (2 rows x 64 k) and pin in registers ----
  float4 W0[16], W1[16];
  {
    const float4* w0p = (const float4*)(Whh + (size_t)jg0 * Hdim + w * 64);
    const float4* w1p = (const float4*)(Whh + (size_t)(jg0 + 1) * Hdim + w * 64);
#pragma unroll
    for (int c = 0; c < 16; ++c) {
      W0[c] = w0p[c];
      W1[c] = w1p[c];
    }
  }
#pragma unroll
  for (int c = 0; c < 16; ++c) {
    asm volatile("" : "+v"(W0[c].x), "+v"(W0[c].y), "+v"(W0[c].z), "+v"(W0[c].w));
    asm volatile("" : "+v"(W1[c].x), "+v"(W1[c].y), "+v"(W1[c].z), "+v"(W1[c].w));
  }

  hL[0][t] = 0.0f;  // h_{-1} = 0
  __syncthreads();

  float* row = xw + (size_t)b * Tdim * Hdim;
  unsigned* hb_row = hbuf + b * Hdim;  // parity-0 base (slow/MALL)
  unsigned* fb_row = fbuf + b * Hdim;  // parity-0 base (fast/L2)
  float xv = is_epi ? row[t] : 0.f;    // xw for step 0

  for (int s = 0; s < Tdim; ++s, row += Hdim) {
    const int sp = s & 1;

    // ---- acquire this wave's h_{s-1} k-slice ----
    if (s > 0 && !is_epi) {
      const size_t off = (size_t)((s - 1) & 1) * (Bdim * Hdim) + t;
      const unsigned want = 1024u | ((unsigned)s & 1023u);
      const unsigned* fp = fb_row + off;
      const unsigned* mp = hb_row + off;
      unsigned v;
      for (;;) {
        unsigned vf, vm;
        ld_dual(fp, mp, vf, vm);
        if ((vf & 2047u) == want) { v = vf; break; }
        if ((vm & 2047u) == want) { v = vm; break; }
      }
      hL[sp][t] = __uint_as_float(v & 0xFFFFF800u);
    }
    // epilogue waves: hL[sp][64w..64w+64) written by THIS wave at s-1 (or init)

    // ---- MAC over k-slice [64w, 64w+64) (wave-uniform LDS broadcasts) ----
    const float4* h4 = (const float4*)&hL[sp][w * 64];
    float a0 = 0.f, a0b = 0.f, a1 = 0.f, a1b = 0.f;
#pragma unroll
    for (int c = 0; c < 16; ++c) {
      const float4 hv = h4[c];
      a0  = fmaf(W0[c].x, hv.x, a0);
      a0b = fmaf(W0[c].y, hv.y, a0b);
      a0  = fmaf(W0[c].z, hv.z, a0);
      a0b = fmaf(W0[c].w, hv.w, a0b);
      a1  = fmaf(W1[c].x, hv.x, a1);
      a1b = fmaf(W1[c].y, hv.y, a1b);
      a1  = fmaf(W1[c].z, hv.z, a1);
      a1b = fmaf(W1[c].w, hv.w, a1b);
    }
    *(float2*)&red[sp][w][2 * l] = make_float2(a0 + a0b, a1 + a1b);
    __syncthreads();  // the ONE barrier per step

    // ---- epilogue on own-quarter waves; peer waves flow into next poll ----
    if (is_epi) {
      const int e = t & 127;
      float y = xv;
#pragma unroll
      for (int w8 = 0; w8 < 8; ++w8) y += red[sp][w8][e];
      const float hn = fast_tanh(y);
      // round to 12 mantissa bits, pack tag in low 11 (atomic dword payload)
      const unsigned bits = (__float_as_uint(hn) + 0x400u) & 0xFFFFF800u;
      const float hq = __uint_as_float(bits);
      const unsigned pv = bits | 1024u | ((unsigned)(s + 1) & 1023u);
      const size_t off = (size_t)sp * (Bdim * Hdim) + t;
      st_l2_sc0(fb_row + off, pv);  // fast: write-through to local L2
      __hip_atomic_store(hb_row + off, pv, __ATOMIC_RELAXED,
                         __HIP_MEMORY_SCOPE_AGENT);  // guaranteed MALL path
      hL[sp ^ 1][t] = hq;  // own k-slice for step s+1 (same-wave write->read)
      if (store_seq) row[t] = hq;
      if (s + 1 < Tdim)
        xv = row[Hdim + t];  // prefetch next step's xw
      else if (h_final != nullptr)
        h_final[(size_t)b * Hdim + t] = hq;
    }
  }
}

// ---------------- final FC ----------------
__global__ __launch_bounds__(256) void fc_kernel(const float* __restrict__ h,
                                                 const float* __restrict__ Wfc,
                                                 const float* __restrict__ bfc,
                                                 float* __restrict__ out) {
  __shared__ float hs[Hdim];
  const int b = blockIdx.x, o = threadIdx.x;
  hs[o] = h[(size_t)b * Hdim + o];
  hs[o + 256] = h[(size_t)b * Hdim + 256 + o];
  __syncthreads();
  float acc = bfc[o];
  const float* wr = Wfc + (size_t)o * Hdim;
#pragma unroll 4
  for (int k = 0; k < Hdim; k += 4) {
    const float4 w = *(const float4*)(wr + k);
    acc = fmaf(w.x, hs[k], acc);
    acc = fmaf(w.y, hs[k + 1], acc);
    acc = fmaf(w.z, hs[k + 2], acc);
    acc = fmaf(w.w, hs[k + 3], acc);
  }
  out[(size_t)b * Odim + o] = acc;
}

extern "C" void kernel_launch(void* const* d_in, const int* in_sizes, int n_in,
                              void* d_out, int out_size, void* d_ws, size_t ws_size,
                              hipStream_t stream) {
  const float* x = (const float*)d_in[0];
  const float* W_ih0 = (const float*)d_in[1];
  const float* W_hh0 = (const float*)d_in[2];
  const float* b_ih0 = (const float*)d_in[3];
  const float* b_hh0 = (const float*)d_in[4];
  const float* W_ih1 = (const float*)d_in[5];
  const float* W_hh1 = (const float*)d_in[6];
  const float* b_ih1 = (const float*)d_in[7];
  const float* b_hh1 = (const float*)d_in[8];
  const float* W_fc = (const float*)d_in[9];
  const float* b_fc = (const float*)d_in[10];
  float* out = (float*)d_out;

  float* A = (float*)d_ws;                               // 134 MB
  unsigned* hbuf0 = (unsigned*)(A + (size_t)Bdim * Tdim * Hdim);  // 256 KB
  unsigned* hbuf1 = hbuf0 + (size_t)2 * Bdim * Hdim;              // 256 KB
  unsigned* fbuf0 = hbuf1 + (size_t)2 * Bdim * Hdim;              // 256 KB
  unsigned* fbuf1 = fbuf0 + (size_t)2 * Bdim * Hdim;              // 256 KB
  float* hT1 = (float*)(fbuf1 + (size_t)2 * Bdim * Hdim);         // 128 KB
  // ws poison (0xAA..): low-11 tag = 682, tags live in [1024,2047] -> no match.
  // Per-layer buffers avoid cross-dispatch tag collisions.

  // A = x @ W_ih0^T + b_ih0 + b_hh0
  gemm_rows<Ddim><<<(Bdim * Tdim) / 64, 1024, 0, stream>>>(x, W_ih0, b_ih0, b_hh0, A);

  // layer-0 scan: A <- out0 (in place)
  {
    float* xwp = A;
    const float* W = W_hh0;
    unsigned* hb = hbuf0;
    unsigned* fb = fbuf0;
    float* hf = nullptr;
    int ss = 1;
    void* args[] = {&xwp, (void*)&W, &hb, &fb, &hf, &ss};
    hipLaunchCooperativeKernel((void*)rnn_scan_coop, dim3(Bdim * 4), dim3(512),
                               args, 0, stream);
  }

  // A <- A @ W_ih1^T + b_ih1 + b_hh1 (in place)
  gemm_rows<Hdim><<<(Bdim * Tdim) / 64, 1024, 0, stream>>>(A, W_ih1, b_ih1, b_hh1, A);

  // layer-1 scan: final hidden only
  {
    float* xwp = A;
    const float* W = W_hh1;
    unsigned* hb = hbuf1;
    unsigned* fb = fbuf1;
    float* hf = hT1;
    int ss = 0;
    void* args[] = {&xwp, (void*)&W, &hb, &fb, &hf, &ss};
    hipLaunchCooperativeKernel((void*)rnn_scan_coop, dim3(Bdim * 4), dim3(512),
                               args, 0, stream);
  }

  // out = hT1 @ W_fc^T + b_fc
  fc_kernel<<<Bdim, Odim, 0, stream>>>(hT1, W_fc, b_fc, out);
}